// Round 4
// baseline (621.045 us; speedup 1.0000x reference)
//
#include <hip/hip_runtime.h>

#define B_  8
#define T_  4096
#define C_  1024
#define TP  4098                 // T + 2 halo rows
#define NW  (1024 * 1024)        // weights per k-slice

typedef __bf16 bf16x8 __attribute__((ext_vector_type(8)));
typedef float  f32x4  __attribute__((ext_vector_type(4)));

__device__ __forceinline__ unsigned short f2bf_rne(float f) {
    unsigned u = __float_as_uint(f);
    u += 0x7FFFu + ((u >> 16) & 1u);
    return (unsigned short)(u >> 16);
}

// async global->LDS, 16B per lane; LDS dest = wave-uniform base + lane*16
#define GLOAD16(g, l)                                                        \
    __builtin_amdgcn_global_load_lds(                                        \
        (const __attribute__((address_space(1))) void*)(g),                  \
        (__attribute__((address_space(3))) void*)(l), 16, 0, 0)

// ---------------------------------------------------------------- init
__global__ __launch_bounds__(256) void init_kernel(
    float* __restrict__ gamma_x, double* __restrict__ wsum,
    unsigned short* __restrict__ xq) {
    const int i = blockIdx.x * 256 + threadIdx.x;   // grid 64*256 = 16384
    if (i < 8192) gamma_x[i] = 0.0f;                // [B][C] absmax accumulators
    if (i == 0) *wsum = 0.0;
    const int r16 = i >> 10;                        // 0..15 pad rows
    const int b = r16 >> 1, side = r16 & 1;
    xq[((size_t)b * TP + (size_t)side * (TP - 1)) * C_ + (i & 1023)] = 0;
}

// ---------------------------------------------------------------- LN stats (fp32 input)
__global__ __launch_bounds__(256) void ln_stats_kernel(
    const float* __restrict__ x, float2* __restrict__ stats) {
    const int row = blockIdx.x;                     // b*T + t
    const float* xr = x + (size_t)row * C_;
    const int tid = threadIdx.x;
    float4 v = *(const float4*)(xr + tid * 4);
    float s  = (v.x + v.y) + (v.z + v.w);
    float s2 = (v.x * v.x + v.y * v.y) + (v.z * v.z + v.w * v.w);
#pragma unroll
    for (int off = 32; off > 0; off >>= 1) {
        s  += __shfl_down(s,  off, 64);
        s2 += __shfl_down(s2, off, 64);
    }
    __shared__ float ps[8];
    const int wave = tid >> 6, lane = tid & 63;
    if (lane == 0) { ps[wave] = s; ps[4 + wave] = s2; }
    __syncthreads();
    if (tid == 0) {
        float ts  = (ps[0] + ps[1]) + (ps[2] + ps[3]);
        float ts2 = (ps[4] + ps[5]) + (ps[6] + ps[7]);
        float mu  = ts * (1.0f / C_);
        float var = fmaxf(ts2 * (1.0f / C_) - mu * mu, 0.0f);
        float rstd = 1.0f / sqrtf(var + 1e-5f);
        stats[row] = make_float2(mu, rstd);
    }
}

// ---------------------------------------------------------------- absmax over T per (b,c)
__global__ __launch_bounds__(256) void absmax_kernel(
    const float* __restrict__ x, const float2* __restrict__ stats,
    const float* __restrict__ lng, const float* __restrict__ lnb,
    float* __restrict__ gamma_x) {
    const int c  = blockIdx.x * 256 + threadIdx.x;  // grid (4, 16, 8)
    const int b  = blockIdx.z;
    const int t0 = blockIdx.y * 256;
    const float g  = lng[c];
    const float be = lnb[c];
    const float* xp = x + ((size_t)(b * T_ + t0)) * C_ + c;
    const float2* st = stats + b * T_ + t0;
    float m = 0.0f;
#pragma unroll 4
    for (int t = 0; t < 256; ++t) {
        float2 s = st[t];
        float xv = xp[(size_t)t * C_];
        m = fmaxf(m, fabsf((xv - s.x) * s.y * g + be));
    }
    // m >= 0 so uint compare == float compare
    atomicMax((unsigned int*)(gamma_x + b * C_ + c), __float_as_uint(m));
}

// ---------------------------------------------------------------- sum |W|
__global__ __launch_bounds__(256) void wsum_kernel(
    const float* __restrict__ W, double* __restrict__ wsum) {
    size_t i = ((size_t)blockIdx.x * 256 + threadIdx.x) * 8;  // grid 1536
    float4 a  = *(const float4*)(W + i);
    float4 b4 = *(const float4*)(W + i + 4);
    float s = fabsf(a.x) + fabsf(a.y) + fabsf(a.z) + fabsf(a.w)
            + fabsf(b4.x) + fabsf(b4.y) + fabsf(b4.z) + fabsf(b4.w);
#pragma unroll
    for (int off = 32; off > 0; off >>= 1) s += __shfl_down(s, off, 64);
    __shared__ float ps[4];
    const int wave = threadIdx.x >> 6, lane = threadIdx.x & 63;
    if (lane == 0) ps[wave] = s;
    __syncthreads();
    if (threadIdx.x == 0) atomicAdd(wsum, (double)((ps[0] + ps[1]) + (ps[2] + ps[3])));
}

// ---------------------------------------------------------------- weight quant + repack wq[k][o][i]
__global__ __launch_bounds__(256) void wquant_kernel(
    const float* __restrict__ W, const double* __restrict__ wsum,
    unsigned short* __restrict__ wq, float* __restrict__ beta_out) {
    const int gid = blockIdx.x * 256 + threadIdx.x;   // (o,i) pair, grid 4096
    const float beta = fmaxf((float)(*wsum * (1.0 / 3145728.0)), 1e-5f);
    if (gid == 0) *beta_out = beta;
    const float* wp = W + (size_t)gid * 3;
#pragma unroll
    for (int k = 0; k < 3; ++k) {
        float s  = wp[k] / beta;                      // ref: clip then round
        float r  = rintf(fminf(fmaxf(s, -1.0f), 1.0f));
        wq[(size_t)k * NW + gid] = f2bf_rne(r);       // {-1,0,1} exact in bf16
    }
}

// ---------------------------------------------------------------- activation quant -> padded xq
__device__ __forceinline__ unsigned short quant1(float xv, float2 s, float g,
                                                 float be, float gam) {
    float xn = (xv - s.x) * s.y * g + be;
    float sc = 127.0f / fmaxf(gam, 1e-5f);
    float r  = rintf(xn * sc);                        // ref: round then clip
    r = fminf(fmaxf(r, -127.0f), 127.0f);
    return f2bf_rne(r);                               // integer |r|<=127: exact
}

__global__ __launch_bounds__(256) void xquant_kernel(
    const float* __restrict__ x, const float2* __restrict__ stats,
    const float* __restrict__ lng, const float* __restrict__ lnb,
    const float* __restrict__ gamma_x, unsigned short* __restrict__ xq) {
    const int row = blockIdx.x;                       // b*T + t, grid 32768
    const int b = row >> 12, t = row & 4095;
    const float2 s = stats[row];
    const int c = threadIdx.x * 4;
    float4 xv = *(const float4*)(x + (size_t)row * C_ + c);
    float4 gv = *(const float4*)(lng + c);
    float4 bv = *(const float4*)(lnb + c);
    float4 gm = *(const float4*)(gamma_x + b * C_ + c);
    ushort4 q;
    q.x = quant1(xv.x, s, gv.x, bv.x, gm.x);
    q.y = quant1(xv.y, s, gv.y, bv.y, gm.y);
    q.z = quant1(xv.z, s, gv.z, bv.z, gm.z);
    q.w = quant1(xv.w, s, gv.w, bv.w, gm.w);
    *(ushort4*)(xq + ((size_t)b * TP + t + 1) * C_ + c) = q;
}

// ---------------------------------------------------------------- conv-as-GEMM, bf16 MFMA (exact int arith)
// block 256 = 4 waves (2x2), tile 128x128, BK=64, 3 k-shift phases
// m97-pattern staging: monotonic lane->address mapping, NO swizzle.
__global__ __launch_bounds__(256, 2) void gemm_kernel(
    const unsigned short* __restrict__ xq,   // [B][TP][C] bf16 (padded)
    const unsigned short* __restrict__ wq,   // [3][O][I] bf16 ternary
    const float* __restrict__ gamma_x,       // [B][C]
    const float* __restrict__ beta_p,        // scalar
    float* __restrict__ out) {               // [B][T][O] fp32
    __shared__ __align__(16) unsigned short ldsA[128 * 64];
    __shared__ __align__(16) unsigned short ldsB[128 * 64];
    const int tid  = threadIdx.x;
    const int wave = tid >> 6, lane = tid & 63;
    const int bidx = blockIdx.x;                 // 256 m-tiles
    const int b  = bidx >> 5;
    const int t0 = (bidx & 31) * 128;
    const int n0 = blockIdx.y * 128;             // 8 n-tiles
    const int wm = (wave >> 1) * 64;
    const int wn = (wave & 1) * 64;

    f32x4 acc[4][4] = {};

    const int sr = wave * 32 + (lane >> 3);      // staging row (+j*8)
    const int g8 = lane & 7;                     // staging granule (identity col)

    for (int k = 0; k < 3; ++k) {
        const unsigned short* Ab = xq + ((size_t)(b * TP + t0 + k)) * C_;
        const unsigned short* Bb = wq + (size_t)k * NW + (size_t)n0 * C_;
        for (int i0 = 0; i0 < 1024; i0 += 64) {
            __syncthreads();                     // protect previous reads
#pragma unroll
            for (int j = 0; j < 4; ++j) {
                int r = sr + j * 8;
                GLOAD16(Ab + (size_t)r * C_ + i0 + g8 * 8, &ldsA[(wave * 32 + j * 8) * 64]);
                GLOAD16(Bb + (size_t)r * C_ + i0 + g8 * 8, &ldsB[(wave * 32 + j * 8) * 64]);
            }
            __syncthreads();                     // drains vmcnt (global_load_lds)
#pragma unroll
            for (int ks = 0; ks < 2; ++ks) {
                const int gk = ks * 4 + (lane >> 4);
                bf16x8 af[4], bfr[4];
#pragma unroll
                for (int mi = 0; mi < 4; ++mi) {
                    int m = wm + mi * 16 + (lane & 15);
                    af[mi] = *(const bf16x8*)&ldsA[m * 64 + gk * 8];
                }
#pragma unroll
                for (int ni = 0; ni < 4; ++ni) {
                    int n = wn + ni * 16 + (lane & 15);
                    bfr[ni] = *(const bf16x8*)&ldsB[n * 64 + gk * 8];
                }
#pragma unroll
                for (int mi = 0; mi < 4; ++mi)
#pragma unroll
                    for (int ni = 0; ni < 4; ++ni)
                        acc[mi][ni] = __builtin_amdgcn_mfma_f32_16x16x32_bf16(
                            af[mi], bfr[ni], acc[mi][ni], 0, 0, 0);
            }
        }
    }

    // epilogue: y = acc * beta * gamma_x[b,o] / 127  (C/D: col=lane&15, row=quad*4+reg)
    const float beta = *beta_p;
    const int col = lane & 15;
    const int rq  = (lane >> 4) * 4;
#pragma unroll
    for (int ni = 0; ni < 4; ++ni) {
        const int o = n0 + wn + ni * 16 + col;
        const float sc = beta * fmaxf(gamma_x[b * C_ + o], 1e-5f) * (1.0f / 127.0f);
#pragma unroll
        for (int mi = 0; mi < 4; ++mi) {
#pragma unroll
            for (int r = 0; r < 4; ++r) {
                const int t = t0 + wm + mi * 16 + rq + r;
                out[((size_t)(b * T_ + t)) * C_ + o] = acc[mi][ni][r] * sc;  // fp32 store
            }
        }
    }
}

// ---------------------------------------------------------------- launch
extern "C" void kernel_launch(void* const* d_in, const int* in_sizes, int n_in,
                              void* d_out, int out_size, void* d_ws, size_t ws_size,
                              hipStream_t stream) {
    const float* x   = (const float*)d_in[0];  // [8,4096,1024] fp32
    const float* lng = (const float*)d_in[1];  // [1024] fp32
    const float* lnb = (const float*)d_in[2];  // [1024] fp32
    const float* W   = (const float*)d_in[3];  // [1024,1024,3] fp32
    float* out = (float*)d_out;                // fp32 output [8,4096,1024]

    char* ws = (char*)d_ws;
    float2*         stats  = (float2*)(ws + 0);          //   262144 B
    float*          gamma  = (float*) (ws + 262144);     //    32768 B
    double*         wsum   = (double*)(ws + 294912);     //        8 B
    float*          beta   = (float*) (ws + 294920);     //        4 B (+pad)
    unsigned short* wq     = (unsigned short*)(ws + 294928);   // 6291456 B
    unsigned short* xq     = (unsigned short*)(ws + 6586384);  // 67141632 B -> 73.7 MB total

    init_kernel    <<<64,    256, 0, stream>>>(gamma, wsum, xq);
    ln_stats_kernel<<<32768, 256, 0, stream>>>(x, stats);
    absmax_kernel  <<<dim3(4, 16, 8), 256, 0, stream>>>(x, stats, lng, lnb, gamma);
    wsum_kernel    <<<1536,  256, 0, stream>>>(W, wsum);
    wquant_kernel  <<<4096,  256, 0, stream>>>(W, wsum, wq, beta);
    xquant_kernel  <<<32768, 256, 0, stream>>>(x, stats, lng, lnb, gamma, xq);
    gemm_kernel    <<<dim3(256, 8), 256, 0, stream>>>(xq, wq, gamma, beta, out);
}